// Round 8
// baseline (2304.549 us; speedup 1.0000x reference)
//
#include <hip/hip_runtime.h>
#include <math.h>

#define Bsz  8192
#define Mdim 512
#define Ndim 2048
#define Kit  16
#define Pk   50
#define EPSv 0.01f

typedef __attribute__((ext_vector_type(8))) short bf16x8;
typedef __attribute__((ext_vector_type(4))) float f32x4;

// ---- bf16 split helpers: x = h + l ----------------------------------------
static __device__ __forceinline__ unsigned short f2bf(float f) {
    unsigned u = __float_as_uint(f);
    return (unsigned short)((u + 0x7fffu + ((u >> 16) & 1u)) >> 16);  // RNE
}
static __device__ __forceinline__ float bf2f(unsigned short h) {
    return __uint_as_float(((unsigned)h) << 16);
}

// ---- async global->LDS, 16B per lane (LDS dest = wave-uniform base) -------
static __device__ __forceinline__ void gl16(const void* g, void* l) {
    __builtin_amdgcn_global_load_lds(
        (const __attribute__((address_space(1))) unsigned int*)g,
        (__attribute__((address_space(3))) unsigned int*)l, 16, 0, 0);
}

#define PIPE_BARRIER() __builtin_amdgcn_s_barrier()

#define MFMA3(acc_, bh_, bl_, ah_, al_)                                           \
    do {                                                                          \
        acc_ = __builtin_amdgcn_mfma_f32_16x16x32_bf16(bh_, ah_, acc_, 0, 0, 0);  \
        acc_ = __builtin_amdgcn_mfma_f32_16x16x32_bf16(bh_, al_, acc_, 0, 0, 0);  \
        acc_ = __builtin_amdgcn_mfma_f32_16x16x32_bf16(bl_, ah_, acc_, 0, 0, 0);  \
    } while (0)

// ---------------------------------------------------------------------------
// One-time: split A into bf16 planes Ah/Al [m][n] and AhT/AlT [n][m].
// ---------------------------------------------------------------------------
__global__ __launch_bounds__(256) void presplit_A(
    const float* __restrict__ A, unsigned short* __restrict__ Ah,
    unsigned short* __restrict__ Al, unsigned short* __restrict__ AhT,
    unsigned short* __restrict__ AlT)
{
    int idx = blockIdx.x * 256 + threadIdx.x;      // 0 .. M*N-1
    int m = idx >> 11, n = idx & (Ndim - 1);
    float a = A[idx];
    unsigned short h = f2bf(a);
    unsigned short l = f2bf(a - bf2f(h));
    Ah[idx] = h; Al[idx] = l;
    AhT[(size_t)n * Mdim + m] = h;
    AlT[(size_t)n * Mdim + m] = l;
}

// ---------------------------------------------------------------------------
// it=0: b = -y, stored as h/l planes. b row layout: [h 512][l 512] shorts.
// ---------------------------------------------------------------------------
__global__ __launch_bounds__(256) void split_negy_kernel(const float* __restrict__ y,
                                                         unsigned short* __restrict__ bS) {
    int i = blockIdx.x * 256 + threadIdx.x;        // float4 index
    float4 v = ((const float4*)y)[i];
    int idx = i * 4;
    int r = idx >> 9, c = idx & 511;
    float f0 = -v.x, f1 = -v.y, f2 = -v.z, f3 = -v.w;
    unsigned short h0 = f2bf(f0), h1 = f2bf(f1), h2 = f2bf(f2), h3 = f2bf(f3);
    ushort4 hv = make_ushort4(h0, h1, h2, h3);
    ushort4 lv = make_ushort4(f2bf(f0 - bf2f(h0)), f2bf(f1 - bf2f(h1)),
                              f2bf(f2 - bf2f(h2)), f2bf(f3 - bf2f(h3)));
    *(ushort4*)(bS + (size_t)r * 1024 + c)       = hv;
    *(ushort4*)(bS + (size_t)r * 1024 + 512 + c) = lv;
}

// ---------------------------------------------------------------------------
// GEMM1 (NT): b[r][m] = sum_n z[r][n]*A[m][n] - y[r][m].
// K-split: 512 thr = 2 K-groups x 4 waves, tile 128x128, per-group K=1024,
// BK=32, NT=32. NEW: one 48-MFMA cluster per K-step with FULL-STEP lookahead:
//   step t: lgkm0; vmcnt0 (STAGE(t+1) issued a full step ago); barrier;
//           STAGE(t+2); LD_ALL(t+1)->nextSet; sched_bar; 48 MFMA(t) on curSet.
// Frag sets double-buffered in registers (named A/B, 2x-unrolled loop).
// Swizzle: slot ^= ((row>>1)&3)<<4 on stage-source AND ds_read.
// ---------------------------------------------------------------------------
__global__ __launch_bounds__(512, 2) void gemm1_mfma(
    const unsigned short* __restrict__ zS,
    const unsigned short* __restrict__ Ah, const unsigned short* __restrict__ Al,
    const float* __restrict__ y, unsigned short* __restrict__ bS)
{
    enum { NT = 32 };                              // per-group K-steps: 1024/32
    const int tid  = threadIdx.x;
    const int lane = tid & 63, w = tid >> 6;       // 8 waves
    const int lm   = lane & 15, quad = lane >> 4;
    const int g    = w >> 2;                       // K-group 0/1
    const int wg   = w & 3;
    const int wrow = (wg >> 1) * 64;               // 2r x 2c within group
    const int wcol = (wg & 1) * 64;

    // bijective XCD swizzle (nwg=256, %8==0)
    int d   = blockIdx.y * gridDim.x + blockIdx.x;
    int sid = (d & 7) * 32 + (d >> 3);
    const int m0 = (sid & 3) * 128, r0 = (sid >> 2) * 128;

    // 2 bufs x 64KB = 128KB; per buf: [g][plane zh|zl|ah|al][8KB]
    __shared__ __attribute__((aligned(16))) unsigned short smem[2 * 32768];

    f32x4 acc[4][4];
#pragma unroll
    for (int i = 0; i < 4; i++)
#pragma unroll
        for (int j = 0; j < 4; j++) acc[i][j] = (f32x4)0.f;

    // staging: each 8KB plane = 8 chunks of 1KB; 2 chunks/wave/plane.
    const unsigned short *zhp[2], *zlp[2], *ahp[2], *alp[2]; int doff[2];
#pragma unroll
    for (int s = 0; s < 2; s++) {
        int off = ((wg * 2 + s) << 10) + lane * 16;           // byte in plane
        int row = off >> 6;                                   // 0..127
        int kb  = (off & 63) ^ (((row >> 1) & 3) << 4);       // swizzled slot
        doff[s] = (wg * 2 + s) << 10;
        int kbase = g * 1024 + (kb >> 1);                     // shorts
        zhp[s]  = zS + (size_t)(r0 + row) * 4096 + kbase;
        zlp[s]  = zS + (size_t)(r0 + row) * 4096 + 2048 + kbase;
        ahp[s]  = Ah + (size_t)(m0 + row) * 2048 + kbase;     // row = m index
        alp[s]  = Al + (size_t)(m0 + row) * 2048 + kbase;
    }

    const int X   = ((lm >> 1) & 3) << 4;
    const int cbx = (quad * 16) ^ X;

    auto STAGE = [&](int t) {
        char* base = (char*)smem + (t & 1) * 65536 + g * 32768;
        const int ko = t * 32;
#pragma unroll
        for (int s = 0; s < 2; s++) {
            gl16(zhp[s] + ko, base +     0 + doff[s]);
            gl16(zlp[s] + ko, base +  8192 + doff[s]);
            gl16(ahp[s] + ko, base + 16384 + doff[s]);
            gl16(alp[s] + ko, base + 24576 + doff[s]);
        }
    };

    auto BUF = [&](int t) -> const char* {
        return (const char*)smem + (t & 1) * 65536 + g * 32768;
    };
    auto LD_FULL = [&](const char* B0, bf16x8 (&zh)[4], bf16x8 (&zl)[4],
                       bf16x8 (&ah)[4], bf16x8 (&al)[4]) {
        const char* zhB = B0, *zlB = B0 + 8192;
        const char* ahB = B0 + 16384, *alB = B0 + 24576;
#pragma unroll
        for (int fi = 0; fi < 4; fi++) {
            int zr = wrow + fi * 16 + lm;
            zh[fi] = *(const bf16x8*)(zhB + zr * 64 + cbx);
            zl[fi] = *(const bf16x8*)(zlB + zr * 64 + cbx);
        }
#pragma unroll
        for (int fj = 0; fj < 4; fj++) {
            int ar = wcol + fj * 16 + lm;
            ah[fj] = *(const bf16x8*)(ahB + ar * 64 + cbx);
            al[fj] = *(const bf16x8*)(alB + ar * 64 + cbx);
        }
    };

    bf16x8 zhA[4], zlA[4], ahA[4], alA[4];
    bf16x8 zhB[4], zlB[4], ahB[4], alB[4];

    // prologue: buf0 staged+read, buf1 staging in flight
    STAGE(0);
    asm volatile("s_waitcnt vmcnt(0)" ::: "memory");
    PIPE_BARRIER();
    STAGE(1);
    LD_FULL(BUF(0), zhA, zlA, ahA, alA);

    auto STEP = [&](int t,
                    bf16x8 (&czh)[4], bf16x8 (&czl)[4], bf16x8 (&cah)[4], bf16x8 (&cal)[4],
                    bf16x8 (&nzh)[4], bf16x8 (&nzl)[4], bf16x8 (&nah)[4], bf16x8 (&nal)[4]) {
        asm volatile("s_waitcnt lgkmcnt(0)" ::: "memory");   // curSet reads done (covered)
        asm volatile("s_waitcnt vmcnt(0)" ::: "memory");     // STAGE(t+1) landed (full-step lead)
        PIPE_BARRIER();
        if (t + 2 < NT) STAGE(t + 2);                        // -> buf(t), reads drained block-wide
        if (t + 1 < NT) LD_FULL(BUF(t + 1), nzh, nzl, nah, nal);  // drains under MFMA
        __builtin_amdgcn_sched_barrier(0);
        __builtin_amdgcn_s_setprio(1);
#pragma unroll
        for (int fi = 0; fi < 4; fi++) {
#pragma unroll
            for (int fj = 0; fj < 4; fj++) {
                MFMA3(acc[fi][fj], czh[fi], czl[fi], cah[fj], cal[fj]);
            }
        }
        __builtin_amdgcn_s_setprio(0);
        __builtin_amdgcn_sched_barrier(0);
    };

    for (int t = 0; t < NT; t += 2) {
        STEP(t,     zhA, zlA, ahA, alA, zhB, zlB, ahB, alB);
        STEP(t + 1, zhB, zlB, ahB, alB, zhA, zlA, ahA, alA);
    }

    // ---- combine groups via LDS (padded stride 132 f32), then epilogue ----
    float* cmb = (float*)smem;                     // 128 x 132 f32 = 67.5KB
    __syncthreads();
    if (g == 1) {
#pragma unroll
        for (int fi = 0; fi < 4; fi++)
#pragma unroll
            for (int fj = 0; fj < 4; fj++)
#pragma unroll
                for (int r = 0; r < 4; r++) {
                    int row = wrow + fi * 16 + quad * 4 + r;
                    int col = wcol + fj * 16 + lm;
                    cmb[row * 132 + col] = acc[fi][fj][r];
                }
    }
    __syncthreads();
    if (g == 0) {
#pragma unroll
        for (int fi = 0; fi < 4; fi++)
#pragma unroll
            for (int fj = 0; fj < 4; fj++)
#pragma unroll
                for (int r = 0; r < 4; r++) {
                    int row = wrow + fi * 16 + quad * 4 + r;
                    int col = wcol + fj * 16 + lm;
                    float bv = acc[fi][fj][r] + cmb[row * 132 + col]
                             - y[(size_t)(r0 + row) * Mdim + (m0 + col)];
                    unsigned short h = f2bf(bv);
                    bS[(size_t)(r0 + row) * 1024 + (m0 + col)]       = h;
                    bS[(size_t)(r0 + row) * 1024 + 512 + (m0 + col)] = f2bf(bv - bf2f(h));
                }
    }
}

// ---------------------------------------------------------------------------
// GEMM2 (NN): c[r][n] = sum_m b[r][m]*A[m][n], c fp32.   (r7 winner, unchanged)
// ---------------------------------------------------------------------------
__global__ __launch_bounds__(512, 2) void gemm2_mfma(
    const unsigned short* __restrict__ bS,
    const unsigned short* __restrict__ AhT, const unsigned short* __restrict__ AlT,
    float* __restrict__ c)
{
    enum { NT = 16 };                              // K = 512 / BK=32
    const int tid  = threadIdx.x;
    const int lane = tid & 63, w = tid >> 6;       // 8 waves
    const int lm   = lane & 15, quad = lane >> 4;
    const int wrow = (w >> 2) * 128;               // 2 row-waves
    const int wcol = (w & 3) * 64;                 // 4 col-waves

    // bijective XCD swizzle (nwg=256, %8==0)
    int d   = blockIdx.y * gridDim.x + blockIdx.x;
    int sid = (d & 7) * 32 + (d >> 3);
    const int n0 = (sid & 7) * 256, r0 = (sid >> 3) * 256;

    __shared__ __attribute__((aligned(16))) unsigned short smem[2 * 32768];

    f32x4 acc[8][4];
#pragma unroll
    for (int i = 0; i < 8; i++)
#pragma unroll
        for (int j = 0; j < 4; j++) acc[i][j] = (f32x4)0.f;

    const unsigned short *bhp[2], *blp[2], *ahp[2], *alp[2]; int doff[2];
#pragma unroll
    for (int s = 0; s < 2; s++) {
        int off = ((w * 2 + s) << 10) + lane * 16;            // byte in plane
        int row = off >> 6;                                   // 0..255
        int kb  = (off & 63) ^ (((row >> 1) & 3) << 4);       // swizzled slot
        doff[s] = (w * 2 + s) << 10;
        bhp[s]  = bS  + (size_t)(r0 + row) * 1024 + (kb >> 1);
        blp[s]  = bS  + (size_t)(r0 + row) * 1024 + 512 + (kb >> 1);
        ahp[s]  = AhT + (size_t)(n0 + row) * 512 + (kb >> 1);
        alp[s]  = AlT + (size_t)(n0 + row) * 512 + (kb >> 1);
    }

    const int X   = ((lm >> 1) & 3) << 4;
    const int cbx = (quad * 16) ^ X;

    auto STAGE = [&](int t) {
        char* base = (char*)smem + (t & 1) * 65536;
        const int ko = t * 32;
#pragma unroll
        for (int s = 0; s < 2; s++) {
            gl16(bhp[s] + ko, base +     0 + doff[s]);
            gl16(blp[s] + ko, base + 16384 + doff[s]);
            gl16(ahp[s] + ko, base + 32768 + doff[s]);
            gl16(alp[s] + ko, base + 49152 + doff[s]);
        }
    };

    auto BUF = [&](int t) -> const char* {
        return (const char*)smem + (t & 1) * 65536;
    };
    auto LD_A = [&](const char* B0, bf16x8 (&ah)[4], bf16x8 (&al)[4]) {
        const char* ahB = B0 + 32768; const char* alB = B0 + 49152;
#pragma unroll
        for (int fj = 0; fj < 4; fj++) {
            int ar = wcol + fj * 16 + lm;
            ah[fj] = *(const bf16x8*)(ahB + ar * 64 + cbx);
            al[fj] = *(const bf16x8*)(alB + ar * 64 + cbx);
        }
    };
    auto LD_B = [&](const char* B0, int rbase, bf16x8 (&bh)[4], bf16x8 (&bl)[4]) {
        const char* bhB = B0; const char* blB = B0 + 16384;
#pragma unroll
        for (int fi = 0; fi < 4; fi++) {
            int br = wrow + (rbase + fi) * 16 + lm;
            bh[fi] = *(const bf16x8*)(bhB + br * 64 + cbx);
            bl[fi] = *(const bf16x8*)(blB + br * 64 + cbx);
        }
    };

    bf16x8 ahf[4], alf[4], b03h[4], b03l[4], b47h[4], b47l[4];

    STAGE(0);
    asm volatile("s_waitcnt vmcnt(0)" ::: "memory");
    PIPE_BARRIER();
    LD_B(BUF(0), 0, b03h, b03l);

    for (int t = 0; t < NT; ++t) {
        const char* B0 = BUF(t);
        // phase A: stage t+1; read a(t) then b47(t); MFMA rows0-3 (b03+a)
        if (t + 1 < NT) STAGE(t + 1);
        LD_A(B0, ahf, alf);                       // needed by this MFMA (a-first)
        LD_B(B0, 4, b47h, b47l);                  // drains under the MFMA
        __builtin_amdgcn_sched_barrier(0);
        __builtin_amdgcn_s_setprio(1);
#pragma unroll
        for (int fi = 0; fi < 4; fi++) {
#pragma unroll
            for (int fj = 0; fj < 4; fj++) {
                MFMA3(acc[fi][fj], b03h[fi], b03l[fi], ahf[fj], alf[fj]);
            }
        }
        __builtin_amdgcn_s_setprio(0);
        __builtin_amdgcn_sched_barrier(0);
        // phase B: buf t+1 ready; read b03(t+1); MFMA rows4-7 (b47+a)
        asm volatile("s_waitcnt vmcnt(0)" ::: "memory");
        PIPE_BARRIER();
        if (t + 1 < NT) LD_B(BUF(t + 1), 0, b03h, b03l);
        __builtin_amdgcn_sched_barrier(0);
        __builtin_amdgcn_s_setprio(1);
#pragma unroll
        for (int fi = 0; fi < 4; fi++) {
#pragma unroll
            for (int fj = 0; fj < 4; fj++) {
                MFMA3(acc[fi + 4][fj], b47h[fi], b47l[fi], ahf[fj], alf[fj]);
            }
        }
        __builtin_amdgcn_s_setprio(0);
        __builtin_amdgcn_sched_barrier(0);
    }

#pragma unroll
    for (int fi = 0; fi < 8; fi++)
#pragma unroll
        for (int fj = 0; fj < 4; fj++)
#pragma unroll
            for (int r = 0; r < 4; r++) {
                int row = r0 + wrow + fi * 16 + quad * 4 + r;
                int col = n0 + wcol + fj * 16 + lm;
                c[(size_t)row * Ndim + col] = acc[fi][fj][r];
            }
}

// ---------------------------------------------------------------------------
// Fused per-row: u = x - gamma*c; exact 50th-largest |u| via 3-pass radix
// (11/11/9 bits, 2048-bin histogram); soft-threshold + overshoot; write x;
// write z planes in place of c.   (r5 version, unchanged)
// ---------------------------------------------------------------------------
__global__ __launch_bounds__(256) void topk_update_kernel(
    float* __restrict__ uz, float* __restrict__ x,
    const float* __restrict__ gamma, const float* __restrict__ theta,
    const float* __restrict__ a_param, const float* __restrict__ vv,
    const float* __restrict__ vu, int it)
{
    const int row = blockIdx.x;
    const int t   = threadIdx.x;
    float* crow = uz + (size_t)row * Ndim;
    float* xrow = x  + (size_t)row * Ndim;
    const float g = gamma[it];

    float4 c0 = *(const float4*)(crow + 4 * t);
    float4 c1 = *(const float4*)(crow + 4 * t + 1024);
    float4 x0 = *(const float4*)(xrow + 4 * t);
    float4 x1 = *(const float4*)(xrow + 4 * t + 1024);
    float cv[8] = { c0.x, c0.y, c0.z, c0.w, c1.x, c1.y, c1.z, c1.w };
    float xv[8] = { x0.x, x0.y, x0.z, x0.w, x1.x, x1.y, x1.z, x1.w };

    float uvals[8];
    unsigned keys[8];
#pragma unroll
    for (int e = 0; e < 8; e++) {
        uvals[e] = xv[e] - g * cv[e];
        keys[e]  = __float_as_uint(fabsf(uvals[e]));
    }

    __shared__ unsigned bins[2048];
    __shared__ unsigned sel[2];
    __shared__ unsigned wsum[4];

    unsigned prefix = 0;
    unsigned k = Pk;
#pragma unroll
    for (int pass = 0; pass < 3; ++pass) {
        const int      shift  = (pass == 0) ? 20 : (pass == 1) ? 9 : 0;
        const unsigned cmask  = (pass == 2) ? 511u : 2047u;
        const unsigned himask = (pass == 0) ? 0u
                              : (pass == 1) ? (0xFFFFFFFFu << 20)
                                            : (0xFFFFFFFFu << 9);
        uint4 zz = { 0u, 0u, 0u, 0u };
        ((uint4*)bins)[t]       = zz;
        ((uint4*)bins)[t + 256] = zz;
        __syncthreads();
#pragma unroll
        for (int e = 0; e < 8; e++) {
            if ((keys[e] & himask) == prefix)
                atomicAdd(&bins[(keys[e] >> shift) & cmask], 1u);
        }
        __syncthreads();
        // hierarchical top-down scan: thread t owns descending ranks [8t,8t+8)
        const int base = 2040 - 8 * t;                 // t=0 -> bins 2040..2047
        uint4 q0 = *(const uint4*)&bins[base];
        uint4 q1 = *(const uint4*)&bins[base + 4];
        unsigned s  = q0.x + q0.y + q0.z + q0.w + q1.x + q1.y + q1.z + q1.w;
        unsigned sc = s;
        const int ln = t & 63;
#pragma unroll
        for (int off = 1; off < 64; off <<= 1) {
            unsigned o = __shfl_up(sc, (unsigned)off);
            if (ln >= off) sc += o;
        }
        if (ln == 63) wsum[t >> 6] = sc;
        __syncthreads();
        unsigned wpre = 0;
#pragma unroll
        for (int ww = 0; ww < 3; ww++)
            if (ww < (t >> 6)) wpre += wsum[ww];
        unsigned pre = wpre + sc - s;                  // exclusive, descending
        if (pre < k && pre + s >= k) {
            unsigned vals[8] = { q1.w, q1.z, q1.y, q1.x, q0.w, q0.z, q0.y, q0.x };
            unsigned p2 = pre;
#pragma unroll
            for (int j = 0; j < 8; j++) {
                unsigned cb = vals[j];
                if (p2 < k && p2 + cb >= k) { sel[0] = (unsigned)(base + 7 - j); sel[1] = k - p2; }
                p2 += cb;
            }
        }
        __syncthreads();
        prefix |= sel[0] << shift;
        k = sel[1];
    }
    const float thresh = __uint_as_float(prefix);

    const float th = theta[it];
    const float ap = a_param[it];
    const bool haveNext = (it + 1) < Kit;
    float tn = 0.f, vn = 0.f, vun = 0.f;
    if (haveNext) { tn = theta[it + 1]; vn = vv[it + 1]; vun = vu[it + 1]; }

    float xo[8];
    unsigned short zh8[8], zl8[8];
#pragma unroll
    for (int e = 0; e < 8; e++) {
        float uval = uvals[e];
        float au   = fabsf(uval);
        bool keep  = au > thresh;
        float shr  = copysignf(fmaxf(au - th, 0.f), uval);
        float xn   = keep ? uval : shr;
        float dlt  = xn - xv[e];
        float ov   = 1.f + ap / (fabsf(dlt) + EPSv);
        float xr   = xv[e] + ov * dlt;
        xo[e] = xr;
        float z = (1.f + tn * vun * __expf(-vn * fabsf(xr))) * xr;
        unsigned short h = f2bf(z);
        zh8[e] = h;
        zl8[e] = f2bf(z - bf2f(h));
    }
    float4 a0 = { xo[0], xo[1], xo[2], xo[3] };
    float4 a1 = { xo[4], xo[5], xo[6], xo[7] };
    *(float4*)(xrow + 4 * t) = a0;
    *(float4*)(xrow + 4 * t + 1024) = a1;
    if (haveNext) {
        unsigned short* zp = (unsigned short*)crow;   // row block: [zh 2048][zl 2048]
        *(ushort4*)(zp + 4 * t)        = make_ushort4(zh8[0], zh8[1], zh8[2], zh8[3]);
        *(ushort4*)(zp + 1024 + 4 * t) = make_ushort4(zh8[4], zh8[5], zh8[6], zh8[7]);
        *(ushort4*)(zp + 2048 + 4 * t) = make_ushort4(zl8[0], zl8[1], zl8[2], zl8[3]);
        *(ushort4*)(zp + 3072 + 4 * t) = make_ushort4(zl8[4], zl8[5], zl8[6], zl8[7]);
    }
}

// ---------------------------------------------------------------------------
extern "C" void kernel_launch(void* const* d_in, const int* in_sizes, int n_in,
                              void* d_out, int out_size, void* d_ws, size_t ws_size,
                              hipStream_t stream) {
    const float* y       = (const float*)d_in[0];   // (B,M)
    const float* A       = (const float*)d_in[1];   // (M,N)
    const float* gamma   = (const float*)d_in[2];
    const float* theta   = (const float*)d_in[3];
    const float* a_param = (const float*)d_in[4];
    const float* v       = (const float*)d_in[5];
    const float* vu      = (const float*)d_in[6];
    // d_in[7] theta_init (unused: multiplies x==0), d_in[8] info (unused)

    float* x = (float*)d_out;                       // (B,N) + 2K zeros

    // workspace layout (88 MB total)
    char* ws = (char*)d_ws;
    float*          uz = (float*)ws;                                  // 64 MB: c fp32 / z planes
    unsigned short* bS = (unsigned short*)(ws + (size_t)Bsz * Ndim * 4); // 16 MB: b planes
    unsigned short* Ah = (unsigned short*)(ws + (size_t)80 * 1024 * 1024);
    unsigned short* Al  = Ah  + (size_t)Mdim * Ndim;                  // 2 MB each
    unsigned short* AhT = Al  + (size_t)Mdim * Ndim;
    unsigned short* AlT = AhT + (size_t)Mdim * Ndim;

    hipMemsetAsync(d_out, 0, (size_t)out_size * sizeof(float), stream);

    dim3 g1(Mdim / 128, Bsz / 128);     // 4 x 64 = 256 blocks (1/CU)
    dim3 g2(Ndim / 256, Bsz / 256);     // 8 x 32 = 256 blocks

    presplit_A<<<(Mdim * Ndim) / 256, dim3(256), 0, stream>>>(A, Ah, Al, AhT, AlT);
    split_negy_kernel<<<(Bsz * Mdim / 4) / 256, dim3(256), 0, stream>>>(y, bS);

    for (int it = 0; it < Kit; ++it) {
        if (it > 0)
            gemm1_mfma<<<g1, dim3(512), 0, stream>>>((const unsigned short*)uz, Ah, Al, y, bS);
        gemm2_mfma<<<g2, dim3(512), 0, stream>>>(bS, AhT, AlT, uz);
        topk_update_kernel<<<Bsz, dim3(256), 0, stream>>>(uz, x, gamma, theta, a_param, v, vu, it);
    }
}